// Round 6
// baseline (436.098 us; speedup 1.0000x reference)
//
#include <hip/hip_runtime.h>
#include <math.h>

#define C 128

typedef unsigned short u16;
typedef __attribute__((ext_vector_type(8))) short short8;
typedef __attribute__((ext_vector_type(4))) float f32x4;
typedef __attribute__((ext_vector_type(4))) u16 u16x4;

__device__ __forceinline__ float b2f(u16 u) {
    union { unsigned i; float f; } x; x.i = (unsigned)u << 16; return x.f;
}
__device__ __forceinline__ u16 f2b(float f) {
    union { float f; unsigned i; } x; x.f = f;
    unsigned r = x.i + 0x7FFFu + ((x.i >> 16) & 1u);
    return (u16)(r >> 16);
}
__device__ __forceinline__ float lrelu(float x) { return x > 0.f ? x : 0.2f * x; }

// ---------------- CSR build (edge_index arrives int32) ----------------

__global__ void hist_kernel(const int* __restrict__ ei, int E, int N,
                            int* __restrict__ count) {
    int total = E + N;
    for (int e = blockIdx.x * blockDim.x + threadIdx.x; e < total;
         e += gridDim.x * blockDim.x) {
        int d = (e < E) ? ei[E + e] : (e - E);
        if ((unsigned)d < (unsigned)N) atomicAdd(&count[d], 1);
    }
}

__global__ __launch_bounds__(1024) void scan_kernel(const int* __restrict__ count,
                                                    int* __restrict__ offs,
                                                    int* __restrict__ cursor, int N) {
    const int T = 1024;
    int tid = threadIdx.x;
    int CH = (N + T - 1) / T;
    int base = tid * CH;
    int s = 0;
    for (int j = 0; j < CH; ++j) {
        int i = base + j;
        if (i < N) s += count[i];
    }
    __shared__ int part[T];
    part[tid] = s;
    __syncthreads();
    for (int off = 1; off < T; off <<= 1) {
        int v = (tid >= off) ? part[tid - off] : 0;
        __syncthreads();
        part[tid] += v;
        __syncthreads();
    }
    int run = (tid == 0) ? 0 : part[tid - 1];
    for (int j = 0; j < CH; ++j) {
        int i = base + j;
        if (i < N) {
            offs[i] = run;
            cursor[i] = run;
            run += count[i];
        }
    }
    if (tid == T - 1) offs[N] = part[T - 1];
}

__global__ void scatter_kernel(const int* __restrict__ ei, int E, int N,
                               int* __restrict__ cursor, int* __restrict__ srcs) {
    int total = E + N;
    for (int e = blockIdx.x * blockDim.x + threadIdx.x; e < total;
         e += gridDim.x * blockDim.x) {
        int sNode, d;
        if (e < E) { sNode = ei[e]; d = ei[E + e]; }
        else       { sNode = e - E; d = sNode; }
        if ((unsigned)d < (unsigned)N && (unsigned)sNode < (unsigned)N) {
            int pos = atomicAdd(&cursor[d], 1);
            srcs[pos] = sNode;
        }
    }
}

// ---------------- fp32 -> bf16 ----------------

__global__ __launch_bounds__(256) void cvt_x_kernel(const float* __restrict__ x,
                                                    u16* __restrict__ xb, int total4) {
    int i = blockIdx.x * blockDim.x + threadIdx.x;
    if (i < total4) {
        float4 v = ((const float4*)x)[i];
        u16x4 o = {f2b(v.x), f2b(v.y), f2b(v.z), f2b(v.w)};
        ((u16x4*)xb)[i] = o;
    }
}

// Wc[l][o][h*128+i] = 0.25 * Wl[h][i][o]  (head-mean folded; [128 cols][512 k] bf16)
__global__ __launch_bounds__(128) void cvt_w_kernel(const float* __restrict__ W1,
                                                    const float* __restrict__ Wr,
                                                    const float* __restrict__ W2,
                                                    u16* __restrict__ Wc) {
    int b = blockIdx.x;            // 0..383
    int l = b >> 7, o = b & 127;
    const float* W = (l == 0) ? W1 : (l == 1) ? Wr : W2;
    int i = threadIdx.x;
    u16* dst = Wc + ((size_t)l * C + o) * 512;
    #pragma unroll
    for (int h = 0; h < 4; ++h) {
        dst[h * C + i] = f2b(0.25f * W[((size_t)h * C + i) * C + o]);
    }
}

// ---------------- W@a vectors: vs/vd[slot][i], 12 slots (W1:0-3, Wr:4-7, W2:8-11) ----

__global__ __launch_bounds__(256) void wvec_kernel(const float* __restrict__ W1,
                                                   const float* __restrict__ as1,
                                                   const float* __restrict__ ad1,
                                                   const float* __restrict__ Wr,
                                                   const float* __restrict__ asr,
                                                   const float* __restrict__ adr,
                                                   const float* __restrict__ W2,
                                                   const float* __restrict__ as2,
                                                   const float* __restrict__ ad2,
                                                   float* __restrict__ vs,
                                                   float* __restrict__ vd) {
    int slot = blockIdx.x;
    const float* W  = (slot < 4) ? W1 : (slot < 8) ? Wr : W2;
    const float* s_ = (slot < 4) ? as1 : (slot < 8) ? asr : as2;
    const float* d_ = (slot < 4) ? ad1 : (slot < 8) ? adr : ad2;
    int h = slot & 3;
    int wave = threadIdx.x >> 6, lane = threadIdx.x & 63;
    int rbase = blockIdx.y * 32 + wave * 8;
    float as0 = s_[h * C + lane], as1v = s_[h * C + 64 + lane];
    float ad0 = d_[h * C + lane], ad1v = d_[h * C + 64 + lane];
    #pragma unroll
    for (int j = 0; j < 8; ++j) {
        int i = rbase + j;
        const float* Wrow = W + ((size_t)h * C + i) * C;
        float w0 = Wrow[lane], w1 = Wrow[64 + lane];
        float ps = w0 * as0 + w1 * as1v;
        float pd = w0 * ad0 + w1 * ad1v;
        #pragma unroll
        for (int m = 32; m; m >>= 1) {
            ps += __shfl_xor(ps, m);
            pd += __shfl_xor(pd, m);
        }
        if (lane == 0) { vs[slot * C + i] = ps; vd[slot * C + i] = pd; }
    }
}

// ---------------- attention scalars: als/ald [N][NH] ----------------

template <int NH>
__global__ __launch_bounds__(256) void al_kernel(const u16* __restrict__ in,
                                                 const float* __restrict__ vs,
                                                 const float* __restrict__ vd,
                                                 float* __restrict__ als,
                                                 float* __restrict__ ald, int N) {
    int node = blockIdx.x * 4 + (threadIdx.x >> 6);
    int lane = threadIdx.x & 63;
    if (node >= N) return;
    float x0 = b2f(in[(size_t)node * C + lane]);
    float x1 = b2f(in[(size_t)node * C + 64 + lane]);
    #pragma unroll
    for (int h = 0; h < NH; ++h) {
        float ps = x0 * vs[h * C + lane] + x1 * vs[h * C + 64 + lane];
        float pd = x0 * vd[h * C + lane] + x1 * vd[h * C + 64 + lane];
        #pragma unroll
        for (int m = 32; m; m >>= 1) {
            ps += __shfl_xor(ps, m);
            pd += __shfl_xor(pd, m);
        }
        if (lane == 0) { als[node * NH + h] = ps; ald[node * NH + h] = pd; }
    }
}

// ---------------- pre-GEMM aggregation: dest[n][h*128+c] = sum_e alpha[e,h]*xsrc[c] ----
// Gathers only the 128-dim input (256 B/edge). Softmax denom in-kernel (no max; logits O(few)).

template <int NH>
__global__ __launch_bounds__(256) void aggx_kernel(const u16* __restrict__ xsrc,
                                                   const float* __restrict__ als,
                                                   const float* __restrict__ ald,
                                                   const int* __restrict__ offs,
                                                   const int* __restrict__ srcs,
                                                   u16* __restrict__ dest, int N) {
    constexpr int STR = 64 / NH;     // lanes per head in phase 1
    constexpr int NHG = NH / 2;      // heads per lane-group in phase 2
    int node = blockIdx.x * 4 + (threadIdx.x >> 6);
    int lane = threadIdx.x & 63;
    if (node >= N) return;
    int beg = offs[node], end = offs[node + 1];

    float adh[NH];
    #pragma unroll
    for (int h = 0; h < NH; ++h) adh[h] = ald[node * NH + h];

    // phase 1: denominators, one head per STR-lane group
    int hd = lane / STR, ofs = lane % STR;
    float adown = ald[node * NH + hd];
    float dn = 0.f;
    for (int i = beg + ofs; i < end; i += STR) {
        dn += __expf(lrelu(als[srcs[i] * NH + hd] + adown));
    }
    #pragma unroll
    for (int m = 1; m < STR; m <<= 1) dn += __shfl_xor(dn, m);
    float inv[NH];
    #pragma unroll
    for (int h = 0; h < NH; ++h) inv[h] = 1.f / __shfl(dn, h * STR);

    // phase 2: weighted gather of x (4 ch/lane, lanes 0-31 = ch 0-127; g picks head half)
    int c0 = (lane & 31) * 4, g = lane >> 5;
    float acc[NHG][4] = {};
    int i = beg;
    for (; i + 2 <= end; i += 2) {
        int s0 = srcs[i], s1 = srcs[i + 1];
        const float* a0 = als + (size_t)s0 * NH;
        const float* a1 = als + (size_t)s1 * NH;
        float w0[NH], w1[NH];
        #pragma unroll
        for (int h = 0; h < NH; ++h) {
            w0[h] = __expf(lrelu(a0[h] + adh[h])) * inv[h];
            w1[h] = __expf(lrelu(a1[h] + adh[h])) * inv[h];
        }
        u16x4 v0 = *(const u16x4*)(xsrc + (size_t)s0 * C + c0);
        u16x4 v1 = *(const u16x4*)(xsrc + (size_t)s1 * C + c0);
        float f0[4], f1[4];
        #pragma unroll
        for (int j = 0; j < 4; ++j) { f0[j] = b2f(v0[j]); f1[j] = b2f(v1[j]); }
        #pragma unroll
        for (int j2 = 0; j2 < NHG; ++j2) {
            float wa = g ? w0[NHG + j2] : w0[j2];
            float wb = g ? w1[NHG + j2] : w1[j2];
            #pragma unroll
            for (int j = 0; j < 4; ++j) acc[j2][j] += wa * f0[j] + wb * f1[j];
        }
    }
    if (i < end) {
        int s0 = srcs[i];
        const float* a0 = als + (size_t)s0 * NH;
        float w0[NH];
        #pragma unroll
        for (int h = 0; h < NH; ++h) w0[h] = __expf(lrelu(a0[h] + adh[h])) * inv[h];
        u16x4 v0 = *(const u16x4*)(xsrc + (size_t)s0 * C + c0);
        float f0[4];
        #pragma unroll
        for (int j = 0; j < 4; ++j) f0[j] = b2f(v0[j]);
        #pragma unroll
        for (int j2 = 0; j2 < NHG; ++j2) {
            float wa = g ? w0[NHG + j2] : w0[j2];
            #pragma unroll
            for (int j = 0; j < 4; ++j) acc[j2][j] += wa * f0[j];
        }
    }
    #pragma unroll
    for (int j2 = 0; j2 < NHG; ++j2) {
        int h = g * NHG + j2;
        u16x4 o = {f2b(acc[j2][0]), f2b(acc[j2][1]), f2b(acc[j2][2]), f2b(acc[j2][3])};
        *(u16x4*)(dest + (size_t)node * (NH * C) + h * C + c0) = o;
    }
}

// ---------------- post-GEMM: out[n][128] = A[n][512] @ Wc^T (+bias) ----------------
// MODE 0: write bf16; 1: write f32; 2: accumulate f32.

template <int MODE>
__global__ __launch_bounds__(256) void gemm2_kernel(const u16* __restrict__ A, int lda,
                                                    const u16* __restrict__ Wc,
                                                    const float* __restrict__ bias,
                                                    u16* __restrict__ outb,
                                                    float* __restrict__ outf, int N) {
    int wave = threadIdx.x >> 6, lane = threadIdx.x & 63;
    int rowBase = blockIdx.x * 64 + wave * 16;
    int colBase = blockIdx.y * 64;
    int r = rowBase + (lane & 15);
    int rl = r < N ? r : N - 1;
    int kg = (lane >> 4) * 8;

    const short8* ap = (const short8*)(A + (size_t)rl * lda + kg);
    short8 a[16];
    #pragma unroll
    for (int kk = 0; kk < 16; ++kk) a[kk] = ap[kk * 4];

    f32x4 acc[4];
    #pragma unroll
    for (int t = 0; t < 4; ++t) acc[t] = (f32x4){0.f, 0.f, 0.f, 0.f};

    #pragma unroll
    for (int t = 0; t < 4; ++t) {
        int col = colBase + t * 16 + (lane & 15);
        const short8* bp = (const short8*)(Wc + (size_t)col * 512 + kg);
        #pragma unroll
        for (int kk = 0; kk < 16; ++kk) {
            acc[t] = __builtin_amdgcn_mfma_f32_16x16x32_bf16(a[kk], bp[kk * 4], acc[t], 0, 0, 0);
        }
    }

    int prow = rowBase + (lane >> 4) * 4;
    #pragma unroll
    for (int t = 0; t < 4; ++t) {
        int col = colBase + t * 16 + (lane & 15);
        float bcol = bias[col];
        #pragma unroll
        for (int j = 0; j < 4; ++j) {
            int rr = prow + j;
            if (rr < N) {
                float v = acc[t][j] + bcol;
                if (MODE == 0) outb[(size_t)rr * C + col] = f2b(v);
                else if (MODE == 1) outf[(size_t)rr * C + col] = v;
                else outf[(size_t)rr * C + col] += v;
            }
        }
    }
}

// ---------------- launch ----------------

extern "C" void kernel_launch(void* const* d_in, const int* in_sizes, int n_in,
                              void* d_out, int out_size, void* d_ws, size_t ws_size,
                              hipStream_t stream) {
    const float* x = (const float*)d_in[0];
    const int* ei = (const int*)d_in[1];
    const float* W1 = (const float*)d_in[2];
    const float* as1 = (const float*)d_in[3];
    const float* ad1 = (const float*)d_in[4];
    const float* b1 = (const float*)d_in[5];
    const float* W2 = (const float*)d_in[6];
    const float* as2 = (const float*)d_in[7];
    const float* ad2 = (const float*)d_in[8];
    const float* b2 = (const float*)d_in[9];
    const float* Wr = (const float*)d_in[10];
    const float* asr = (const float*)d_in[11];
    const float* adr = (const float*)d_in[12];
    const float* br = (const float*)d_in[13];

    int N = in_sizes[0] / C;   // 20000
    int E = in_sizes[1] / 2;   // 320000
    int ET = E + N;

    size_t sz_xb    = (size_t)N * C * 2;
    size_t sz_h1b   = (size_t)N * C * 2;
    size_t sz_aggA  = (size_t)N * 1024 * 2;   // heads 0-3: layer1; 4-7: residual
    size_t sz_aggB  = (size_t)N * 512 * 2;
    size_t sz_wc    = (size_t)3 * C * 512 * 2;
    size_t sz_v     = (size_t)12 * C * 4;
    size_t sz_al8   = (size_t)N * 8 * 4;
    size_t sz_count = (size_t)N * 4;
    size_t sz_offs  = (size_t)(N + 4) * 4;
    size_t sz_srcs  = (size_t)ET * 4;
    size_t required = sz_xb + sz_h1b + sz_aggA + sz_aggB + sz_wc + 2 * sz_v +
                      2 * sz_al8 + 2 * sz_count + sz_offs + sz_srcs;
    if (ws_size < required) return;

    char* w = (char*)d_ws;
    u16* xb = (u16*)w;        w += sz_xb;
    u16* h1b = (u16*)w;       w += sz_h1b;
    u16* aggA = (u16*)w;      w += sz_aggA;
    u16* aggB = (u16*)w;      w += sz_aggB;
    u16* Wc = (u16*)w;        w += sz_wc;
    float* vs = (float*)w;    w += sz_v;
    float* vd = (float*)w;    w += sz_v;
    float* als = (float*)w;   w += sz_al8;
    float* ald = (float*)w;   w += sz_al8;
    int* count = (int*)w;     w += sz_count;
    int* cursor = (int*)w;    w += sz_count;
    int* offs = (int*)w;      w += sz_offs;
    int* srcs = (int*)w;      w += sz_srcs;
    float* out = (float*)d_out;

    const u16* Wc1 = Wc;
    const u16* Wcr = Wc + (size_t)C * 512;
    const u16* Wc2 = Wc + (size_t)2 * C * 512;

    hipMemsetAsync(count, 0, sz_count, stream);
    hist_kernel<<<512, 256, 0, stream>>>(ei, E, N, count);
    scan_kernel<<<1, 1024, 0, stream>>>(count, offs, cursor, N);
    scatter_kernel<<<512, 256, 0, stream>>>(ei, E, N, cursor, srcs);

    int total4 = (N * C) / 4;
    cvt_x_kernel<<<(total4 + 255) / 256, 256, 0, stream>>>(x, xb, total4);
    cvt_w_kernel<<<384, 128, 0, stream>>>(W1, Wr, W2, Wc);
    wvec_kernel<<<dim3(12, 4), 256, 0, stream>>>(W1, as1, ad1, Wr, asr, adr,
                                                 W2, as2, ad2, vs, vd);

    int nwb = (N + 3) / 4;
    dim3 ggrid((N + 63) / 64, 2);

    // group A: layer1 + residual (share the x gather)
    al_kernel<8><<<nwb, 256, 0, stream>>>(xb, vs, vd, als, ald, N);
    aggx_kernel<8><<<nwb, 256, 0, stream>>>(xb, als, ald, offs, srcs, aggA, N);
    gemm2_kernel<0><<<ggrid, 256, 0, stream>>>(aggA, 1024, Wc1, b1, h1b, out, N);
    gemm2_kernel<1><<<ggrid, 256, 0, stream>>>(aggA + 512, 1024, Wcr, br, h1b, out, N);

    // group B: layer2
    al_kernel<4><<<nwb, 256, 0, stream>>>(h1b, vs + 8 * C, vd + 8 * C, als, ald, N);
    aggx_kernel<4><<<nwb, 256, 0, stream>>>(h1b, als, ald, offs, srcs, aggB, N);
    gemm2_kernel<2><<<ggrid, 256, 0, stream>>>(aggB, 512, Wc2, b2, h1b, out, N);
}

// Round 7
// 386.782 us; speedup vs baseline: 1.1275x; 1.1275x over previous
//
#include <hip/hip_runtime.h>
#include <math.h>

#define C 128

typedef unsigned short u16;
typedef __attribute__((ext_vector_type(8))) short short8;
typedef __attribute__((ext_vector_type(4))) float f32x4;
typedef __attribute__((ext_vector_type(4))) u16 u16x4;

__device__ __forceinline__ float b2f(u16 u) {
    union { unsigned i; float f; } x; x.i = (unsigned)u << 16; return x.f;
}
__device__ __forceinline__ u16 f2b(float f) {
    union { float f; unsigned i; } x; x.f = f;
    unsigned r = x.i + 0x7FFFu + ((x.i >> 16) & 1u);
    return (u16)(r >> 16);
}
__device__ __forceinline__ float lrelu(float x) { return x > 0.f ? x : 0.2f * x; }

// ---------------- CSR build (edge_index arrives int32) ----------------

__global__ void hist_kernel(const int* __restrict__ ei, int E, int N,
                            int* __restrict__ count) {
    int total = E + N;
    for (int e = blockIdx.x * blockDim.x + threadIdx.x; e < total;
         e += gridDim.x * blockDim.x) {
        int d = (e < E) ? ei[E + e] : (e - E);
        if ((unsigned)d < (unsigned)N) atomicAdd(&count[d], 1);
    }
}

__global__ __launch_bounds__(1024) void scan_kernel(const int* __restrict__ count,
                                                    int* __restrict__ offs,
                                                    int* __restrict__ cursor, int N) {
    const int T = 1024;
    int tid = threadIdx.x;
    int CH = (N + T - 1) / T;
    int base = tid * CH;
    int s = 0;
    for (int j = 0; j < CH; ++j) {
        int i = base + j;
        if (i < N) s += count[i];
    }
    __shared__ int part[T];
    part[tid] = s;
    __syncthreads();
    for (int off = 1; off < T; off <<= 1) {
        int v = (tid >= off) ? part[tid - off] : 0;
        __syncthreads();
        part[tid] += v;
        __syncthreads();
    }
    int run = (tid == 0) ? 0 : part[tid - 1];
    for (int j = 0; j < CH; ++j) {
        int i = base + j;
        if (i < N) {
            offs[i] = run;
            cursor[i] = run;
            run += count[i];
        }
    }
    if (tid == T - 1) offs[N] = part[T - 1];
}

__global__ void scatter_kernel(const int* __restrict__ ei, int E, int N,
                               int* __restrict__ cursor, int* __restrict__ srcs,
                               int* __restrict__ dsts) {
    int total = E + N;
    for (int e = blockIdx.x * blockDim.x + threadIdx.x; e < total;
         e += gridDim.x * blockDim.x) {
        int sNode, d;
        if (e < E) { sNode = ei[e]; d = ei[E + e]; }
        else       { sNode = e - E; d = sNode; }
        if ((unsigned)d < (unsigned)N && (unsigned)sNode < (unsigned)N) {
            int pos = atomicAdd(&cursor[d], 1);
            srcs[pos] = sNode;
            dsts[pos] = d;
        }
    }
}

// ---------------- fp32 -> bf16 ----------------

__global__ __launch_bounds__(256) void cvt_x_kernel(const float* __restrict__ x,
                                                    u16* __restrict__ xb, int total4) {
    int i = blockIdx.x * blockDim.x + threadIdx.x;
    if (i < total4) {
        float4 v = ((const float4*)x)[i];
        u16x4 o = {f2b(v.x), f2b(v.y), f2b(v.z), f2b(v.w)};
        ((u16x4*)xb)[i] = o;
    }
}

// Wc[l][o][h*128+i] = 0.25 * Wl[h][i][o]  (head-mean folded; [128 cols][512 k] bf16)
__global__ __launch_bounds__(128) void cvt_w_kernel(const float* __restrict__ W1,
                                                    const float* __restrict__ Wr,
                                                    const float* __restrict__ W2,
                                                    u16* __restrict__ Wc) {
    int b = blockIdx.x;            // 0..383
    int l = b >> 7, o = b & 127;
    const float* W = (l == 0) ? W1 : (l == 1) ? Wr : W2;
    int i = threadIdx.x;
    u16* dst = Wc + ((size_t)l * C + o) * 512;
    #pragma unroll
    for (int h = 0; h < 4; ++h) {
        dst[h * C + i] = f2b(0.25f * W[((size_t)h * C + i) * C + o]);
    }
}

// ---------------- W@a vectors: vs/vd[slot][i], 12 slots (W1:0-3, Wr:4-7, W2:8-11) ----

__global__ __launch_bounds__(256) void wvec_kernel(const float* __restrict__ W1,
                                                   const float* __restrict__ as1,
                                                   const float* __restrict__ ad1,
                                                   const float* __restrict__ Wr,
                                                   const float* __restrict__ asr,
                                                   const float* __restrict__ adr,
                                                   const float* __restrict__ W2,
                                                   const float* __restrict__ as2,
                                                   const float* __restrict__ ad2,
                                                   float* __restrict__ vs,
                                                   float* __restrict__ vd) {
    int slot = blockIdx.x;
    const float* W  = (slot < 4) ? W1 : (slot < 8) ? Wr : W2;
    const float* s_ = (slot < 4) ? as1 : (slot < 8) ? asr : as2;
    const float* d_ = (slot < 4) ? ad1 : (slot < 8) ? adr : ad2;
    int h = slot & 3;
    int wave = threadIdx.x >> 6, lane = threadIdx.x & 63;
    int rbase = blockIdx.y * 32 + wave * 8;
    float as0 = s_[h * C + lane], as1v = s_[h * C + 64 + lane];
    float ad0 = d_[h * C + lane], ad1v = d_[h * C + 64 + lane];
    #pragma unroll
    for (int j = 0; j < 8; ++j) {
        int i = rbase + j;
        const float* Wrow = W + ((size_t)h * C + i) * C;
        float w0 = Wrow[lane], w1 = Wrow[64 + lane];
        float ps = w0 * as0 + w1 * as1v;
        float pd = w0 * ad0 + w1 * ad1v;
        #pragma unroll
        for (int m = 32; m; m >>= 1) {
            ps += __shfl_xor(ps, m);
            pd += __shfl_xor(pd, m);
        }
        if (lane == 0) { vs[slot * C + i] = ps; vd[slot * C + i] = pd; }
    }
}

// ---------------- attention scalars: als/ald [N][NH] ----------------

template <int NH>
__global__ __launch_bounds__(256) void al_kernel(const u16* __restrict__ in,
                                                 const float* __restrict__ vs,
                                                 const float* __restrict__ vd,
                                                 float* __restrict__ als,
                                                 float* __restrict__ ald, int N) {
    int node = blockIdx.x * 4 + (threadIdx.x >> 6);
    int lane = threadIdx.x & 63;
    if (node >= N) return;
    float x0 = b2f(in[(size_t)node * C + lane]);
    float x1 = b2f(in[(size_t)node * C + 64 + lane]);
    #pragma unroll
    for (int h = 0; h < NH; ++h) {
        float ps = x0 * vs[h * C + lane] + x1 * vs[h * C + 64 + lane];
        float pd = x0 * vd[h * C + lane] + x1 * vd[h * C + 64 + lane];
        #pragma unroll
        for (int m = 32; m; m >>= 1) {
            ps += __shfl_xor(ps, m);
            pd += __shfl_xor(pd, m);
        }
        if (lane == 0) { als[node * NH + h] = ps; ald[node * NH + h] = pd; }
    }
}

// ---------------- edge-parallel unnormalized weights: w[i][h] ----------------

template <int NH>
__global__ __launch_bounds__(256) void ew_kernel(const float* __restrict__ als,
                                                 const float* __restrict__ ald,
                                                 const int* __restrict__ srcs,
                                                 const int* __restrict__ dsts,
                                                 float* __restrict__ wout, int ET) {
    int i = blockIdx.x * blockDim.x + threadIdx.x;
    if (i >= ET) return;
    int s = srcs[i], d = dsts[i];
    const float* as_ = als + (size_t)s * NH;
    const float* ad_ = ald + (size_t)d * NH;
    float* wo = wout + (size_t)i * NH;
    #pragma unroll
    for (int h = 0; h < NH; ++h) {
        wo[h] = __expf(lrelu(as_[h] + ad_[h]));
    }
}

// ---------------- pre-GEMM aggregation: dest[n][h*128+c] = inv[h]*sum_e w[e,h]*xsrc[c] --

template <int NH>
__global__ __launch_bounds__(256) void aggx_kernel(const u16* __restrict__ xsrc,
                                                   const float* __restrict__ wgt,
                                                   const int* __restrict__ offs,
                                                   const int* __restrict__ srcs,
                                                   u16* __restrict__ dest, int N) {
    constexpr int NHG = NH / 2;
    constexpr int EP = 64 / NH;        // edges per phase-1 pass
    int node = blockIdx.x * 4 + (threadIdx.x >> 6);
    int lane = threadIdx.x & 63;
    if (node >= N) return;
    int beg = offs[node], end = offs[node + 1];
    int len = end - beg;
    int g = lane >> 5;

    // phase 1: denominators from contiguous w. lane = io*NH + h
    int h1 = lane & (NH - 1);
    int io = lane >> (NH == 8 ? 3 : 2);
    float dn = 0.f;
    for (int i = io; i < len; i += EP) {
        dn += wgt[(size_t)(beg + i) * NH + h1];
    }
    #pragma unroll
    for (int m = NH; m < 64; m <<= 1) dn += __shfl_xor(dn, m);
    float inv[NHG];
    #pragma unroll
    for (int j2 = 0; j2 < NHG; ++j2) inv[j2] = 1.f / __shfl(dn, g * NHG + j2);

    // phase 2: unnormalized weighted gather; 4-edge unroll
    int c0 = (lane & 31) * 4;
    float acc[NHG][4] = {};
    int i = beg;
    for (; i + 4 <= end; i += 4) {
        int s0 = srcs[i], s1 = srcs[i + 1], s2 = srcs[i + 2], s3 = srcs[i + 3];
        float w0[NHG], w1[NHG], w2[NHG], w3[NHG];
        #pragma unroll
        for (int j2 = 0; j2 < NHG; ++j2) {
            w0[j2] = wgt[(size_t)(i + 0) * NH + g * NHG + j2];
            w1[j2] = wgt[(size_t)(i + 1) * NH + g * NHG + j2];
            w2[j2] = wgt[(size_t)(i + 2) * NH + g * NHG + j2];
            w3[j2] = wgt[(size_t)(i + 3) * NH + g * NHG + j2];
        }
        u16x4 v0 = *(const u16x4*)(xsrc + (size_t)s0 * C + c0);
        u16x4 v1 = *(const u16x4*)(xsrc + (size_t)s1 * C + c0);
        u16x4 v2 = *(const u16x4*)(xsrc + (size_t)s2 * C + c0);
        u16x4 v3 = *(const u16x4*)(xsrc + (size_t)s3 * C + c0);
        float f0[4], f1[4], f2[4], f3[4];
        #pragma unroll
        for (int j = 0; j < 4; ++j) {
            f0[j] = b2f(v0[j]); f1[j] = b2f(v1[j]);
            f2[j] = b2f(v2[j]); f3[j] = b2f(v3[j]);
        }
        #pragma unroll
        for (int j2 = 0; j2 < NHG; ++j2) {
            #pragma unroll
            for (int j = 0; j < 4; ++j) {
                acc[j2][j] += w0[j2] * f0[j] + w1[j2] * f1[j] +
                              w2[j2] * f2[j] + w3[j2] * f3[j];
            }
        }
    }
    for (; i < end; ++i) {
        int s0 = srcs[i];
        float w0[NHG];
        #pragma unroll
        for (int j2 = 0; j2 < NHG; ++j2) {
            w0[j2] = wgt[(size_t)i * NH + g * NHG + j2];
        }
        u16x4 v0 = *(const u16x4*)(xsrc + (size_t)s0 * C + c0);
        float f0[4];
        #pragma unroll
        for (int j = 0; j < 4; ++j) f0[j] = b2f(v0[j]);
        #pragma unroll
        for (int j2 = 0; j2 < NHG; ++j2) {
            #pragma unroll
            for (int j = 0; j < 4; ++j) acc[j2][j] += w0[j2] * f0[j];
        }
    }

    #pragma unroll
    for (int j2 = 0; j2 < NHG; ++j2) {
        int h = g * NHG + j2;
        u16x4 o = {f2b(acc[j2][0] * inv[j2]), f2b(acc[j2][1] * inv[j2]),
                   f2b(acc[j2][2] * inv[j2]), f2b(acc[j2][3] * inv[j2])};
        *(u16x4*)(dest + (size_t)node * (NH * C) + h * C + c0) = o;
    }
}

// ---------------- post-GEMM: out[n][128] = A[n][512] @ Wc^T (+bias) ----------------
// MODE 0: write bf16; 1: write f32; 2: accumulate f32.

template <int MODE>
__global__ __launch_bounds__(256) void gemm2_kernel(const u16* __restrict__ A, int lda,
                                                    const u16* __restrict__ Wc,
                                                    const float* __restrict__ bias,
                                                    u16* __restrict__ outb,
                                                    float* __restrict__ outf, int N) {
    int wave = threadIdx.x >> 6, lane = threadIdx.x & 63;
    int rowBase = blockIdx.x * 64 + wave * 16;
    int colBase = blockIdx.y * 64;
    int r = rowBase + (lane & 15);
    int rl = r < N ? r : N - 1;
    int kg = (lane >> 4) * 8;

    const short8* ap = (const short8*)(A + (size_t)rl * lda + kg);
    short8 a[16];
    #pragma unroll
    for (int kk = 0; kk < 16; ++kk) a[kk] = ap[kk * 4];

    f32x4 acc[4];
    #pragma unroll
    for (int t = 0; t < 4; ++t) acc[t] = (f32x4){0.f, 0.f, 0.f, 0.f};

    #pragma unroll
    for (int t = 0; t < 4; ++t) {
        int col = colBase + t * 16 + (lane & 15);
        const short8* bp = (const short8*)(Wc + (size_t)col * 512 + kg);
        #pragma unroll
        for (int kk = 0; kk < 16; ++kk) {
            acc[t] = __builtin_amdgcn_mfma_f32_16x16x32_bf16(a[kk], bp[kk * 4], acc[t], 0, 0, 0);
        }
    }

    int prow = rowBase + (lane >> 4) * 4;
    #pragma unroll
    for (int t = 0; t < 4; ++t) {
        int col = colBase + t * 16 + (lane & 15);
        float bcol = bias[col];
        #pragma unroll
        for (int j = 0; j < 4; ++j) {
            int rr = prow + j;
            if (rr < N) {
                float v = acc[t][j] + bcol;
                if (MODE == 0) outb[(size_t)rr * C + col] = f2b(v);
                else if (MODE == 1) outf[(size_t)rr * C + col] = v;
                else outf[(size_t)rr * C + col] += v;
            }
        }
    }
}

// ---------------- launch ----------------

extern "C" void kernel_launch(void* const* d_in, const int* in_sizes, int n_in,
                              void* d_out, int out_size, void* d_ws, size_t ws_size,
                              hipStream_t stream) {
    const float* x = (const float*)d_in[0];
    const int* ei = (const int*)d_in[1];
    const float* W1 = (const float*)d_in[2];
    const float* as1 = (const float*)d_in[3];
    const float* ad1 = (const float*)d_in[4];
    const float* b1 = (const float*)d_in[5];
    const float* W2 = (const float*)d_in[6];
    const float* as2 = (const float*)d_in[7];
    const float* ad2 = (const float*)d_in[8];
    const float* b2 = (const float*)d_in[9];
    const float* Wr = (const float*)d_in[10];
    const float* asr = (const float*)d_in[11];
    const float* adr = (const float*)d_in[12];
    const float* br = (const float*)d_in[13];

    int N = in_sizes[0] / C;   // 20000
    int E = in_sizes[1] / 2;   // 320000
    int ET = E + N;

    size_t sz_xb    = (size_t)N * C * 2;
    size_t sz_h1b   = (size_t)N * C * 2;
    size_t sz_aggA  = (size_t)N * 1024 * 2;   // heads 0-3: layer1; 4-7: residual
    size_t sz_aggB  = (size_t)N * 512 * 2;
    size_t sz_wc    = (size_t)3 * C * 512 * 2;
    size_t sz_v     = (size_t)12 * C * 4;
    size_t sz_al8   = (size_t)N * 8 * 4;
    size_t sz_count = (size_t)N * 4;
    size_t sz_offs  = (size_t)(N + 4) * 4;
    size_t sz_srcs  = (size_t)ET * 4;
    size_t sz_w     = (size_t)ET * 8 * 4;     // reused for NH=4
    size_t required = sz_xb + sz_h1b + sz_aggA + sz_aggB + sz_wc + 2 * sz_v +
                      2 * sz_al8 + 2 * sz_count + sz_offs + 2 * sz_srcs + sz_w;
    if (ws_size < required) return;

    char* w = (char*)d_ws;
    u16* xb = (u16*)w;        w += sz_xb;
    u16* h1b = (u16*)w;       w += sz_h1b;
    u16* aggA = (u16*)w;      w += sz_aggA;
    u16* aggB = (u16*)w;      w += sz_aggB;
    u16* Wc = (u16*)w;        w += sz_wc;
    float* vs = (float*)w;    w += sz_v;
    float* vd = (float*)w;    w += sz_v;
    float* als = (float*)w;   w += sz_al8;
    float* ald = (float*)w;   w += sz_al8;
    int* count = (int*)w;     w += sz_count;
    int* cursor = (int*)w;    w += sz_count;
    int* offs = (int*)w;      w += sz_offs;
    int* srcs = (int*)w;      w += sz_srcs;
    int* dsts = (int*)w;      w += sz_srcs;
    float* wgt = (float*)w;   w += sz_w;
    float* out = (float*)d_out;

    const u16* Wc1 = Wc;
    const u16* Wcr = Wc + (size_t)C * 512;
    const u16* Wc2 = Wc + (size_t)2 * C * 512;

    hipMemsetAsync(count, 0, sz_count, stream);
    hist_kernel<<<512, 256, 0, stream>>>(ei, E, N, count);
    scan_kernel<<<1, 1024, 0, stream>>>(count, offs, cursor, N);
    scatter_kernel<<<512, 256, 0, stream>>>(ei, E, N, cursor, srcs, dsts);

    int total4 = (N * C) / 4;
    cvt_x_kernel<<<(total4 + 255) / 256, 256, 0, stream>>>(x, xb, total4);
    cvt_w_kernel<<<384, 128, 0, stream>>>(W1, Wr, W2, Wc);
    wvec_kernel<<<dim3(12, 4), 256, 0, stream>>>(W1, as1, ad1, Wr, asr, adr,
                                                 W2, as2, ad2, vs, vd);

    int nwb = (N + 3) / 4;
    int neb = (ET + 255) / 256;
    dim3 ggrid((N + 63) / 64, 2);

    // group A: layer1 + residual (share the x gather)
    al_kernel<8><<<nwb, 256, 0, stream>>>(xb, vs, vd, als, ald, N);
    ew_kernel<8><<<neb, 256, 0, stream>>>(als, ald, srcs, dsts, wgt, ET);
    aggx_kernel<8><<<nwb, 256, 0, stream>>>(xb, wgt, offs, srcs, aggA, N);
    gemm2_kernel<0><<<ggrid, 256, 0, stream>>>(aggA, 1024, Wc1, b1, h1b, out, N);
    gemm2_kernel<1><<<ggrid, 256, 0, stream>>>(aggA + 512, 1024, Wcr, br, h1b, out, N);

    // group B: layer2
    al_kernel<4><<<nwb, 256, 0, stream>>>(h1b, vs + 8 * C, vd + 8 * C, als, ald, N);
    ew_kernel<4><<<neb, 256, 0, stream>>>(als, ald, srcs, dsts, wgt, ET);
    aggx_kernel<4><<<nwb, 256, 0, stream>>>(h1b, wgt, offs, srcs, aggB, N);
    gemm2_kernel<2><<<ggrid, 256, 0, stream>>>(aggB, 512, Wc2, b2, h1b, out, N);
}